// Round 1
// baseline (393.903 us; speedup 1.0000x reference)
//
#include <hip/hip_runtime.h>

// Problem: inputs (B=32, L=720, C=862) f32. Output (T=4, B, C, L) f32 spikes.
// x is broadcast across T, so the LIF scan is element-wise: 4 spikes per input
// scalar. Memory-bound: 79.4 MB read + 317.8 MB write => ~63 us roofline.
// Transpose (L,C)->(C,L) done via 32x32 LDS tile, +1 pad (conflict-free).

#define B_DIM 32
#define L_DIM 720
#define C_DIM 862
#define T_STEPS 4
#define TILE 32

__global__ __launch_bounds__(256)
void lif_repeat_encoder(const float* __restrict__ in, float* __restrict__ out) {
    __shared__ float tile[TILE][TILE + 1];

    const int b  = blockIdx.z;
    const int l0 = blockIdx.x * TILE;
    const int c0 = blockIdx.y * TILE;
    const int tx = threadIdx.x;   // 0..31
    const int ty = threadIdx.y;   // 0..7

    const float* __restrict__ inb = in + (size_t)b * L_DIM * C_DIM;

    // ---- Load phase: coalesced along c (input inner dim) ----
    {
        const int c = c0 + tx;
        if (c < C_DIM) {
#pragma unroll
            for (int k = 0; k < 4; ++k) {
                const int l = l0 + ty + 8 * k;
                if (l < L_DIM) {
                    tile[ty + 8 * k][tx] = inb[(size_t)l * C_DIM + c];
                }
            }
        }
    }
    __syncthreads();

    // ---- Write phase: coalesced along l (output inner dim) ----
    const int l = l0 + tx;
    if (l >= L_DIM) return;

    const size_t plane = (size_t)B_DIM * C_DIM * L_DIM;

#pragma unroll
    for (int k = 0; k < 4; ++k) {
        const int c = c0 + ty + 8 * k;
        if (c >= C_DIM) continue;

        // LDS read: addr = tx*33 + (ty+8k) -> bank (tx+const)%32, conflict-free
        const float x = tile[tx][ty + 8 * k];

        // LIF recurrence, exact reference semantics:
        //   v <- v + (x - v)/2 ;  s = (v - 1 >= 0) ;  v <- s ? 0 : v
        float v = 0.0f;
        float s[T_STEPS];
#pragma unroll
        for (int t = 0; t < T_STEPS; ++t) {
            v = v + (x - v) * 0.5f;
            const float sp = (v - 1.0f >= 0.0f) ? 1.0f : 0.0f;
            s[t] = sp;
            v = (sp != 0.0f) ? 0.0f : v;
        }

        const size_t base = ((size_t)b * C_DIM + c) * L_DIM + l;
#pragma unroll
        for (int t = 0; t < T_STEPS; ++t) {
            out[(size_t)t * plane + base] = s[t];
        }
    }
}

extern "C" void kernel_launch(void* const* d_in, const int* in_sizes, int n_in,
                              void* d_out, int out_size, void* d_ws, size_t ws_size,
                              hipStream_t stream) {
    const float* in = (const float*)d_in[0];
    float* out = (float*)d_out;

    dim3 block(32, 8, 1);
    dim3 grid((L_DIM + TILE - 1) / TILE,   // 23
              (C_DIM + TILE - 1) / TILE,   // 27
              B_DIM);                      // 32

    lif_repeat_encoder<<<grid, block, 0, stream>>>(in, out);
}

// Round 2
// 379.411 us; speedup vs baseline: 1.0382x; 1.0382x over previous
//
#include <hip/hip_runtime.h>

// Problem: inputs (B=32, L=720, C=862) f32. Output (T=4, B, C, L) f32 spikes.
// x is broadcast across T, so the LIF scan is element-wise: 4 spikes per input
// scalar. Memory-bound: 79.4 MB read + 317.8 MB write => ~63 us roofline.
//
// R2: 64x64 tile, vectorized 16B/lane stores (output rows are 16B aligned:
// L=720 floats = 2880 B), float2 input loads (input rows only 8B aligned:
// C=862 floats = 3448 B), LDS transpose with row stride 68 (b128-aligned,
// 2-way bank aliasing = free), nontemporal output stores (318 MB stream).

#define B_DIM 32
#define L_DIM 720
#define C_DIM 862
#define T_STEPS 4
#define TL 64          // tile extent in l
#define TC 64          // tile extent in c
#define LROW 68        // padded LDS row stride (floats), multiple of 4 for b128

typedef float v2f __attribute__((ext_vector_type(2)));
typedef float v4f __attribute__((ext_vector_type(4)));

__global__ __launch_bounds__(256)
void lif_repeat_encoder(const float* __restrict__ in, float* __restrict__ out) {
    __shared__ float smem[TC * LROW];   // [c_local][l_local], transposed tile

    const int b   = blockIdx.z;
    const int l0  = blockIdx.x * TL;
    const int c0  = blockIdx.y * TC;
    const int tid = threadIdx.x;

    const float* __restrict__ inb = in + (size_t)b * (L_DIM * C_DIM);

    // ---- Load phase: coalesced along c (input inner dim), transpose to LDS ----
    {
        const int c4   = (tid & 15) << 2;  // 0,4,...,60
        const int lrow = tid >> 4;         // 0..15
#pragma unroll
        for (int p = 0; p < 4; ++p) {
            const int ll = lrow + p * 16;
            const int l  = l0 + ll;
            if (l < L_DIM) {
                const int c = c0 + c4;
                const float* src = inb + (size_t)l * C_DIM + c;
                if (c + 3 < C_DIM) {
                    // two 8B loads (rows are 8B-aligned, not 16B: 3448 % 16 == 8)
                    const v2f a = *(const v2f*)(src);
                    const v2f d = *(const v2f*)(src + 2);
                    smem[(c4 + 0) * LROW + ll] = a.x;
                    smem[(c4 + 1) * LROW + ll] = a.y;
                    smem[(c4 + 2) * LROW + ll] = d.x;
                    smem[(c4 + 3) * LROW + ll] = d.y;
                } else {
#pragma unroll
                    for (int i = 0; i < 4; ++i) {
                        if (c + i < C_DIM)
                            smem[(c4 + i) * LROW + ll] = src[i];
                    }
                }
            }
        }
    }
    __syncthreads();

    // ---- Compute + store phase: coalesced along l (output inner dim) ----
    const int l4   = (tid & 15) << 2;  // 0,4,...,60
    const int crow = tid >> 4;         // 0..3 within wave, 0..15 across block
    const int l    = l0 + l4;
    if (l >= L_DIM) return;  // 720 % 4 == 0 and l0 % 64 == 0 => full float4 valid

    const size_t plane = (size_t)B_DIM * C_DIM * L_DIM;

#pragma unroll
    for (int q = 0; q < 4; ++q) {
        const int cl = crow + q * 16;
        const int c  = c0 + cl;
        if (c >= C_DIM) continue;

        // b128 LDS read: base + cl*68 + l4, 16B aligned (68 % 4 == 0, l4 % 4 == 0)
        const v4f x = *(const v4f*)(smem + cl * LROW + l4);

        // LIF recurrence per component, exact reference semantics:
        //   v <- v + (x - v)/2 ;  s = (v - 1 >= 0) ;  v <- s ? 0 : v
        float sx[T_STEPS], sy[T_STEPS], sz[T_STEPS], sw[T_STEPS];
        {
            float v0 = 0.f, v1 = 0.f, v2 = 0.f, v3 = 0.f;
#pragma unroll
            for (int t = 0; t < T_STEPS; ++t) {
                v0 += (x.x - v0) * 0.5f;
                v1 += (x.y - v1) * 0.5f;
                v2 += (x.z - v2) * 0.5f;
                v3 += (x.w - v3) * 0.5f;
                sx[t] = (v0 >= 1.0f) ? 1.0f : 0.0f;
                sy[t] = (v1 >= 1.0f) ? 1.0f : 0.0f;
                sz[t] = (v2 >= 1.0f) ? 1.0f : 0.0f;
                sw[t] = (v3 >= 1.0f) ? 1.0f : 0.0f;
                v0 = (v0 >= 1.0f) ? 0.0f : v0;
                v1 = (v1 >= 1.0f) ? 0.0f : v1;
                v2 = (v2 >= 1.0f) ? 0.0f : v2;
                v3 = (v3 >= 1.0f) ? 0.0f : v3;
            }
        }

        const size_t base = ((size_t)b * C_DIM + c) * L_DIM + l;
#pragma unroll
        for (int t = 0; t < T_STEPS; ++t) {
            v4f o;
            o.x = sx[t]; o.y = sy[t]; o.z = sz[t]; o.w = sw[t];
            // output rows 16B aligned: L=720 floats = 2880 B, plane % 16 == 0
            __builtin_nontemporal_store(o, (v4f*)(out + (size_t)t * plane + base));
        }
    }
}

extern "C" void kernel_launch(void* const* d_in, const int* in_sizes, int n_in,
                              void* d_out, int out_size, void* d_ws, size_t ws_size,
                              hipStream_t stream) {
    const float* in = (const float*)d_in[0];
    float* out = (float*)d_out;

    dim3 block(256, 1, 1);
    dim3 grid((L_DIM + TL - 1) / TL,   // 12
              (C_DIM + TC - 1) / TC,   // 14
              B_DIM);                  // 32

    lif_repeat_encoder<<<grid, block, 0, stream>>>(in, out);
}

// Round 3
// 369.176 us; speedup vs baseline: 1.0670x; 1.0277x over previous
//
#include <hip/hip_runtime.h>

// Problem: inputs (B=32, L=720, C=862) f32. Output (T=4, B, C, L) f32 spikes.
// x is broadcast across T => element-wise 4-step LIF. Memory-bound:
// 79.4 MB read + 317.8 MB write => ~63 us kernel roofline.
//
// R3: write-contiguity restructure. Block = (b, 16 c-rows) x FULL L row.
// Each (c,t) store stream is a full 2880 B row; block emits 4 contiguous
// 46 KB regions (one per t-plane) instead of scattered 256 B chunks
// (R2's suspected DRAM page-thrash). Reads: one 64 B line per (l, c-tile),
// zero over-fetch. LDS [c][l] stride 724 (b128-aligned, <=2-way banks).

#define B_DIM 32
#define L_DIM 720
#define C_DIM 862
#define T_STEPS 4
#define TC 16
#define SL 724   // LDS l-stride per c row (floats): %4==0 (b128), %8==4 (banks)

typedef float v2f __attribute__((ext_vector_type(2)));
typedef float v4f __attribute__((ext_vector_type(4)));

__global__ __launch_bounds__(256)
void lif_repeat_encoder(const float* __restrict__ in, float* __restrict__ out) {
    __shared__ float sm[TC * SL];   // 46,336 B

    const int b   = blockIdx.y;
    const int c0  = blockIdx.x * TC;
    const int tid = threadIdx.x;

    const float* __restrict__ inb = in + (size_t)b * (L_DIM * C_DIM);

    // ---- Load phase: rows l, 2 consecutive c per lane (float2, 8B-aligned:
    // row stride 3448 B and c even keep %8==0). 8 lanes cover the 16-c tile
    // per row; 256 threads = 32 rows per round; 4 rounds batched for MLP.
    {
        const int cl2 = (tid & 7) << 1;   // c_local: 0,2,...,14
        const int c   = c0 + cl2;
        const int r0  = tid >> 3;         // 0..31
        if (c < C_DIM) {                  // tail tile (c0=848) has 14 cols: cl2=14 inactive
            for (int base = 0; base < L_DIM; base += 128) {
                v2f v[4];
#pragma unroll
                for (int u = 0; u < 4; ++u) {
                    const int r = base + r0 + 32 * u;
                    if (r < L_DIM)
                        v[u] = *(const v2f*)(inb + (size_t)r * C_DIM + c);
                }
#pragma unroll
                for (int u = 0; u < 4; ++u) {
                    const int r = base + r0 + 32 * u;
                    if (r < L_DIM) {
                        sm[cl2 * SL + r]       = v[u].x;
                        sm[(cl2 + 1) * SL + r] = v[u].y;
                    }
                }
            }
        }
    }
    __syncthreads();

    // ---- Store phase: wave w handles c_local = 4w..4w+3; per (c,t) the wave
    // writes the FULL 720-float row in 3 float4 rounds (64+64+52 lanes).
    const int wave = tid >> 6;   // 0..3
    const int lane = tid & 63;
    const size_t plane = (size_t)B_DIM * C_DIM * L_DIM;

#pragma unroll
    for (int q = 0; q < 4; ++q) {
        const int cl = wave * 4 + q;
        const int c  = c0 + cl;
        if (c >= C_DIM) continue;

        const size_t rowbase = ((size_t)b * C_DIM + c) * L_DIM;

#pragma unroll
        for (int round = 0; round < 3; ++round) {
            const int j = lane + 64 * round;       // float4 index within row
            if (j >= L_DIM / 4) break;             // 180 float4 per row

            const v4f x = *(const v4f*)(sm + cl * SL + 4 * j);

            // LIF: v += (x - v)*0.5 ; s = (v>=1) ; v = s ? 0 : v   (exact ref)
            float sx[T_STEPS], sy[T_STEPS], sz[T_STEPS], sw[T_STEPS];
            float v0 = 0.f, v1 = 0.f, v2 = 0.f, v3 = 0.f;
#pragma unroll
            for (int t = 0; t < T_STEPS; ++t) {
                v0 += (x.x - v0) * 0.5f;
                v1 += (x.y - v1) * 0.5f;
                v2 += (x.z - v2) * 0.5f;
                v3 += (x.w - v3) * 0.5f;
                sx[t] = (v0 >= 1.0f) ? 1.0f : 0.0f;
                sy[t] = (v1 >= 1.0f) ? 1.0f : 0.0f;
                sz[t] = (v2 >= 1.0f) ? 1.0f : 0.0f;
                sw[t] = (v3 >= 1.0f) ? 1.0f : 0.0f;
                v0 = (v0 >= 1.0f) ? 0.0f : v0;
                v1 = (v1 >= 1.0f) ? 0.0f : v1;
                v2 = (v2 >= 1.0f) ? 0.0f : v2;
                v3 = (v3 >= 1.0f) ? 0.0f : v3;
            }

#pragma unroll
            for (int t = 0; t < T_STEPS; ++t) {
                v4f o;
                o.x = sx[t]; o.y = sy[t]; o.z = sz[t]; o.w = sw[t];
                __builtin_nontemporal_store(
                    o, (v4f*)(out + (size_t)t * plane + rowbase + 4 * j));
            }
        }
    }
}

extern "C" void kernel_launch(void* const* d_in, const int* in_sizes, int n_in,
                              void* d_out, int out_size, void* d_ws, size_t ws_size,
                              hipStream_t stream) {
    const float* in = (const float*)d_in[0];
    float* out = (float*)d_out;

    dim3 block(256, 1, 1);
    dim3 grid((C_DIM + TC - 1) / TC,   // 54
              B_DIM,                   // 32
              1);

    lif_repeat_encoder<<<grid, block, 0, stream>>>(in, out);
}